// Round 17
// baseline (178.188 us; speedup 1.0000x reference)
//
#include <hip/hip_runtime.h>

typedef short bf16x8 __attribute__((ext_vector_type(8)));
typedef float f32x4 __attribute__((ext_vector_type(4)));
typedef float f32x16 __attribute__((ext_vector_type(16)));
typedef unsigned short u16;
typedef unsigned short u16x8 __attribute__((ext_vector_type(8)));
typedef unsigned int u32;
typedef unsigned int u32x2 __attribute__((ext_vector_type(2)));
typedef unsigned int u32x4 __attribute__((ext_vector_type(4)));

#define MFMA16(a, b, c) __builtin_amdgcn_mfma_f32_16x16x32_bf16((a), (b), (c), 0, 0, 0)
#define MFMA32(a, b, c) __builtin_amdgcn_mfma_f32_32x32x16_bf16((a), (b), (c), 0, 0, 0)

__device__ __forceinline__ u16 f2bf(float f) {
  unsigned u = __builtin_bit_cast(unsigned, f);
  return (u16)((u + 0x7fffu + ((u >> 16) & 1u)) >> 16);
}

__device__ __forceinline__ unsigned cvt_pk_bf16(float lo, float hi) {
  unsigned r;
  asm("v_cvt_pk_bf16_f32 %0, %1, %2" : "=v"(r) : "v"(lo), "v"(hi));
  return r;
}

__device__ __forceinline__ void gload_lds16(const u16* g, u16* lds) {
  __builtin_amdgcn_global_load_lds((__attribute__((address_space(1))) void*)g,
                                   (__attribute__((address_space(3))) void*)lds,
                                   16, 0, 0);
}

// Publish LDS writes + block barrier WITHOUT draining vmcnt.
__device__ __forceinline__ void publish_barrier() {
  asm volatile("s_waitcnt lgkmcnt(0)" ::: "memory");
  __builtin_amdgcn_sched_barrier(0);
  __builtin_amdgcn_s_barrier();
}

// ---------------- fp32 -> bf16 conversion (x + 4 weight mats) ----------------
__global__ __launch_bounds__(256) void cvt_all(
    const float* __restrict__ x, const float* __restrict__ w0,
    const float* __restrict__ w1, const float* __restrict__ w2,
    const float* __restrict__ w3, u16* __restrict__ xb, u16* __restrict__ wb) {
  long i = (long)(blockIdx.x * 256 + threadIdx.x) * 8;
  const float* src; u16* dst; long off;
  if (i < 4194304) { src = x; dst = xb; off = i; }
  else {
    long k = i - 4194304; int w = (int)(k >> 20); off = k & 1048575;
    src = (w == 0) ? w0 : (w == 1) ? w1 : (w == 2) ? w2 : w3;
    dst = wb + (long)w * 1048576;
  }
  float4 a = *(const float4*)(src + off);
  float4 b = *(const float4*)(src + off + 4);
  u16x8 o;
  o[0] = f2bf(a.x); o[1] = f2bf(a.y); o[2] = f2bf(a.z); o[3] = f2bf(a.w);
  o[4] = f2bf(b.x); o[5] = f2bf(b.y); o[6] = f2bf(b.z); o[7] = f2bf(b.w);
  *(u16x8*)(dst + off) = o;
}

// ---------------- GEMM  C[M,N] = A[M,K] * B[N,K]^T  (bf16 in, fp32 acc) -----
template <int MODE>
__global__ __launch_bounds__(256) void gemm_bt(
    const u16* __restrict__ A, const u16* __restrict__ Bw,
    u16* __restrict__ Co, float* __restrict__ Cf, const float* __restrict__ bias) {
  constexpr int K = 1024;
  __shared__ u16 As[128 * 32];
  __shared__ u16 Bs[128 * 32];
  const int tid = threadIdx.x, w = tid >> 6, l = tid & 63;
  const int lg = l >> 4, lr = l & 15;
  const int mb = blockIdx.x;
  int mat, nb;
  if (MODE == 0) { mat = blockIdx.y >> 3; nb = blockIdx.y & 7; }
  else           { mat = 0;               nb = blockIdx.y;     }
  const u16* __restrict__ Bp = Bw + (long)mat * 1048576;
  const int wr = w >> 1, wc = w & 1;
  f32x4 acc[4][4] = {};
  const int srow = (l >> 2), scol = (l & 3) * 8;
  for (int kt = 0; kt < K / 32; ++kt) {
    const int kb = kt * 32;
    __syncthreads();
#pragma unroll
    for (int i = 0; i < 2; ++i) {
      int r = w * 32 + i * 16 + srow;
      gload_lds16(A  + (long)(mb * 128 + r) * K + kb + scol, &As[(w * 2 + i) * 512]);
      gload_lds16(Bp + (long)(nb * 128 + r) * K + kb + scol, &Bs[(w * 2 + i) * 512]);
    }
    __syncthreads();
    bf16x8 af[4], bf[4];
#pragma unroll
    for (int m = 0; m < 4; ++m) af[m] = *(const bf16x8*)&As[(wr * 64 + m * 16 + lr) * 32 + lg * 8];
#pragma unroll
    for (int n = 0; n < 4; ++n) bf[n] = *(const bf16x8*)&Bs[(wc * 64 + n * 16 + lr) * 32 + lg * 8];
#pragma unroll
    for (int m = 0; m < 4; ++m)
#pragma unroll
      for (int n = 0; n < 4; ++n)
        acc[m][n] = MFMA16(af[m], bf[n], acc[m][n]);
  }
  const int row0 = mb * 128 + wr * 64, col0 = nb * 128 + wc * 64;
#pragma unroll
  for (int m = 0; m < 4; ++m)
#pragma unroll
    for (int n = 0; n < 4; ++n)
#pragma unroll
      for (int rr = 0; rr < 4; ++rr) {
        int row = row0 + m * 16 + lg * 4 + rr;
        int col = col0 + n * 16 + lr;
        float v = acc[m][n][rr];
        if (MODE == 0) {
          if (mat == 0) v *= 0.18033688011112042f;  // 0.125 * log2(e)
          Co[(long)mat * 4194304 + (long)row * 1024 + col] = f2bf(v);
        } else {
          Cf[(long)row * 1024 + col] = v + bias[col];
        }
      }
}

// ---------------- flash attention: 2 tiles per barrier interval ------------
// R16 got 103.5us with cross-barrier skew. R17: two tiles between barriers
// (4-buffer K/V rings, read pair p / stage pair p^2 disjoint). Halves the
// barrier count (64->32); QKT(a)+QKT(b) = 32 back-to-back MFMAs with 4
// independent acc chains; FINISH(a)'s TRANS/VALU interleaves with QKT(b)
// MFMAs in scheduler. R10 tested this on the broken K-path base (confounded);
// retry on the healthy base (K-LDS staged + permlane pack).
__global__ __launch_bounds__(256) void attn(
    const u16* __restrict__ Qg, const u16* __restrict__ Kg,
    const u16* __restrict__ Vg, u16* __restrict__ Og) {
  __shared__ u16 Ksb[4 * 4096];   // 4-ring K tiles [64][64 u16], XOR-swizzled
  __shared__ u16 Vsb[4 * 4608];   // 4-ring V^T [d][k] pitch 72, dword-swizzled
  const int tid = threadIdx.x, w = tid >> 6, l = tid & 63;
  const int l31 = l & 31, hi = l >> 5;

  // XCD clustering: lin%8 = XCD; 2 heads/XCD -> K+V set 2 MB < 4 MB L2/XCD.
  const int lin = blockIdx.x;
  const int xcd = lin & 7, idx = lin >> 3;
  const int head = xcd * 2 + (idx >> 5), qt = idx & 31;
  const int hb = head * 64;
  const int q0 = qt * 128 + w * 32;

  const u16* __restrict__ Kh = Kg + hb;

  bf16x8 qf[4];
#pragma unroll
  for (int st = 0; st < 4; ++st)
    qf[st] = *(const bf16x8*)&Qg[(long)(q0 + l31) * 1024 + hb + st * 16 + hi * 8];

  f32x16 o0 = {}, o1 = {};
  f32x4 lsv = {};

  // V staging: thread stages rows (2kr, 2kr+1), octet c8 (coalesced b128)
  const int kr = tid >> 3, c8 = tid & 7;
  const u16* Vgp = Vg + hb + c8 * 8;
  bf16x8 va0, va1, vb0, vb1;

  // K staging: linear gload_lds dest + pre-swizzled global source (rule 21)
  const int krow = tid >> 3;
  const int ksrc = (((tid & 7) * 16) ^ ((krow & 7) << 4)) >> 1;  // u16 units
  u16* kdst = Ksb + w * 512;  // wave-uniform base; HW adds lane*16B

// stage K tiles t_, t_+1 into bufs b0_, b1_
#define KSTAGE2(t_, b0_, b1_)                                                 \
  {                                                                           \
    gload_lds16(Kh + (long)((t_) * 64 + krow) * 1024 + ksrc,                  \
                kdst + (b0_) * 4096);                                         \
    gload_lds16(Kh + (long)((t_) * 64 + 32 + krow) * 1024 + ksrc,             \
                kdst + (b0_) * 4096 + 2048);                                  \
    gload_lds16(Kh + (long)((t_) * 64 + 64 + krow) * 1024 + ksrc,             \
                kdst + (b1_) * 4096);                                         \
    gload_lds16(Kh + (long)((t_) * 64 + 96 + krow) * 1024 + ksrc,             \
                kdst + (b1_) * 4096 + 2048);                                  \
  }

// load V tiles t_, t_+1 into regs
#define VLOAD2(t_)                                                    \
  {                                                                   \
    long r0_ = (long)(t_) * 64 + kr * 2;                              \
    va0 = *(const bf16x8*)&Vgp[r0_ * 1024];                           \
    va1 = *(const bf16x8*)&Vgp[(r0_ + 1) * 1024];                     \
    vb0 = *(const bf16x8*)&Vgp[(r0_ + 64) * 1024];                    \
    vb1 = *(const bf16x8*)&Vgp[(r0_ + 65) * 1024];                    \
  }

// V^T pack via v_perm_b32, write va->buf b0_, vb->buf b1_
#define VWRITE2(b0_, b1_)                                                  \
  {                                                                        \
    const int cw = (kr ^ (c8 << 2)) * 2;                                   \
    u16* da_ = Vsb + (b0_) * 4608;                                         \
    u16* db_ = Vsb + (b1_) * 4608;                                         \
    u32x4 A_ = __builtin_bit_cast(u32x4, va0);                             \
    u32x4 B_ = __builtin_bit_cast(u32x4, va1);                             \
    u32x4 C_ = __builtin_bit_cast(u32x4, vb0);                             \
    u32x4 D_ = __builtin_bit_cast(u32x4, vb1);                             \
    _Pragma("unroll") for (int dd = 0; dd < 4; ++dd) {                     \
      u32 pe = __builtin_amdgcn_perm(B_[dd], A_[dd], 0x05040100u);         \
      u32 po = __builtin_amdgcn_perm(B_[dd], A_[dd], 0x07060302u);         \
      u32 qe = __builtin_amdgcn_perm(D_[dd], C_[dd], 0x05040100u);         \
      u32 qo = __builtin_amdgcn_perm(D_[dd], C_[dd], 0x07060302u);         \
      *(u32*)&da_[(c8 * 8 + 2 * dd) * 72 + cw] = pe;                       \
      *(u32*)&da_[(c8 * 8 + 2 * dd + 1) * 72 + cw] = po;                   \
      *(u32*)&db_[(c8 * 8 + 2 * dd) * 72 + cw] = qe;                       \
      *(u32*)&db_[(c8 * 8 + 2 * dd + 1) * 72 + cw] = qo;                   \
    }                                                                      \
  }

#define KFRAG(kf_, db_)                                                       \
  {                                                                           \
    _Pragma("unroll") for (int tt = 0; tt < 2; ++tt)                          \
      _Pragma("unroll") for (int st = 0; st < 4; ++st) {                      \
        const int row_ = tt * 32 + l31;                                       \
        const int boff_ = (st * 32 + hi * 16) ^ ((row_ & 7) << 4);            \
        (kf_)[tt][st] =                                                       \
            *(const bf16x8*)&Ksb[(db_) * 4096 + row_ * 64 + (boff_ >> 1)];    \
      }                                                                       \
  }

#define QKT(S0_, S1_, db_)                                                    \
  {                                                                           \
    bf16x8 kf_[2][4];                                                         \
    KFRAG(kf_, db_);                                                          \
    S0_ = (f32x16){};                                                         \
    S1_ = (f32x16){};                                                         \
    __builtin_amdgcn_s_setprio(1);                                            \
    _Pragma("unroll") for (int st = 0; st < 4; ++st) {                        \
      S0_ = MFMA32(kf_[0][st], qf[st], S0_);                                  \
      S1_ = MFMA32(kf_[1][st], qf[st], S1_);                                  \
    }                                                                         \
    __builtin_amdgcn_s_setprio(0);                                            \
  }

// P pack via permlane32_swap (T12): one swap fills both frag words.
#define PACKCHUNK(SX, base_, pb_)                                             \
  {                                                                           \
    u32 a0_ = cvt_pk_bf16((SX)[(base_) + 0], (SX)[(base_) + 1]);              \
    u32 b0_ = cvt_pk_bf16((SX)[(base_) + 4], (SX)[(base_) + 5]);              \
    u32 a1_ = cvt_pk_bf16((SX)[(base_) + 2], (SX)[(base_) + 3]);              \
    u32 b1_ = cvt_pk_bf16((SX)[(base_) + 6], (SX)[(base_) + 7]);              \
    u32x2 r0_ = __builtin_amdgcn_permlane32_swap(a0_, b0_, false, false);     \
    u32x2 r1_ = __builtin_amdgcn_permlane32_swap(a1_, b1_, false, false);     \
    u32x4 fv_;                                                                \
    fv_[0] = r0_[0]; fv_[1] = r1_[0]; fv_[2] = r0_[1]; fv_[3] = r1_[1];       \
    (pb_) = __builtin_bit_cast(bf16x8, fv_);                                  \
  }

// softmax-finish + PV for one tile (V buf db_), lsv accumulate
#define FINISH(SC0, SC1, db_)                                                 \
  {                                                                           \
    _Pragma("unroll") for (int r = 0; r < 16; ++r) {                          \
      SC0[r] = __builtin_amdgcn_exp2f(SC0[r]);                                \
      SC1[r] = __builtin_amdgcn_exp2f(SC1[r]);                                \
    }                                                                         \
    const u16* myV = Vsb + (db_) * 4608;                                      \
    _Pragma("unroll") for (int c = 0; c < 4; ++c) {                           \
      bf16x8 pb;                                                              \
      if (c < 2) { PACKCHUNK(SC0, (c & 1) * 8, pb); }                         \
      else       { PACKCHUNK(SC1, (c & 1) * 8, pb); }                         \
      const int sw0 = ((8 * c + 4 * hi) ^ (((l31 >> 3) & 7) << 2)) * 2;       \
      const int sw1 = ((8 * c + 4 * hi) ^ ((((l31 + 32) >> 3) & 7) << 2)) * 2;\
      bf16x8 vf0 = *(const bf16x8*)&myV[l31 * 72 + sw0];                      \
      bf16x8 vf1 = *(const bf16x8*)&myV[(32 + l31) * 72 + sw1];               \
      __builtin_amdgcn_s_setprio(1);                                          \
      o0 = MFMA32(vf0, pb, o0);                                               \
      o1 = MFMA32(vf1, pb, o1);                                               \
      __builtin_amdgcn_s_setprio(0);                                          \
    }                                                                         \
    _Pragma("unroll") for (int r2 = 0; r2 < 4; ++r2)                          \
      _Pragma("unroll") for (int j = 0; j < 4; ++j)                           \
        lsv[j] += SC0[r2 * 4 + j] + SC1[r2 * 4 + j];                          \
  }

// interval: tiles (2i, 2i+1) from bufs (p, p+1); stage (2i+2, 2i+3) -> p^2
#define INTERVAL(i_, p_, stage_)                                              \
  {                                                                           \
    if (stage_) {                                                             \
      KSTAGE2(2 * (i_) + 2, (p_) ^ 2, ((p_) ^ 2) + 1);                        \
      VLOAD2(2 * (i_) + 2);                                                   \
    }                                                                         \
    f32x16 Sa0, Sa1, Sb0, Sb1;                                                \
    QKT(Sa0, Sa1, p_);                                                        \
    QKT(Sb0, Sb1, (p_) + 1);                                                  \
    FINISH(Sa0, Sa1, p_);                                                     \
    FINISH(Sb0, Sb1, (p_) + 1);                                               \
    if (stage_) VWRITE2((p_) ^ 2, ((p_) ^ 2) + 1);                            \
    publish_barrier();                                                        \
  }

  // prologue: stage tiles 0,1 (K bufs 0,1 + V bufs 0,1), drain, barrier
  KSTAGE2(0, 0, 1);
  VLOAD2(0);
  VWRITE2(0, 1);
  asm volatile("s_waitcnt vmcnt(0)" ::: "memory");
  publish_barrier();

  for (int j = 0; j < 15; ++j) {   // intervals 0..29
    INTERVAL(2 * j, 0, true);
    INTERVAL(2 * j + 1, 2, true);
  }
  INTERVAL(30, 0, true);           // stages tiles 62,63 -> bufs 2,3
  INTERVAL(31, 2, false);          // final pair, no staging

  // epilogue: reduce ls over both k-half lanes, normalize, store ctx^T
  {
    float sls = (lsv[0] + lsv[1]) + (lsv[2] + lsv[3]);
    float s = sls + __shfl_xor(sls, 32);
    float inv = 1.0f / s;
#pragma unroll
    for (int dt = 0; dt < 2; ++dt) {
#pragma unroll
      for (int r2 = 0; r2 < 4; ++r2) {
        float v0 = dt ? o1[r2 * 4 + 0] : o0[r2 * 4 + 0];
        float v1 = dt ? o1[r2 * 4 + 1] : o0[r2 * 4 + 1];
        float v2 = dt ? o1[r2 * 4 + 2] : o0[r2 * 4 + 2];
        float v3 = dt ? o1[r2 * 4 + 3] : o0[r2 * 4 + 3];
        uint2 pk;
        pk.x = cvt_pk_bf16(v0 * inv, v1 * inv);
        pk.y = cvt_pk_bf16(v2 * inv, v3 * inv);
        const int d0 = dt * 32 + 8 * r2 + 4 * hi;
        *(uint2*)&Og[(long)(q0 + l31) * 1024 + hb + d0] = pk;
      }
    }
  }
#undef KSTAGE2
#undef VLOAD2
#undef VWRITE2
#undef KFRAG
#undef QKT
#undef PACKCHUNK
#undef FINISH
#undef INTERVAL
}

extern "C" void kernel_launch(void* const* d_in, const int* in_sizes, int n_in,
                              void* d_out, int out_size, void* d_ws, size_t ws_size,
                              hipStream_t stream) {
  const float* x  = (const float*)d_in[0];
  const float* Wq = (const float*)d_in[1];
  const float* Wk = (const float*)d_in[2];
  const float* Wv = (const float*)d_in[3];
  const float* Wo = (const float*)d_in[4];
  const float* bo = (const float*)d_in[5];
  float* out = (float*)d_out;

  u16* xb  = (u16*)d_ws;            // 4096x1024 bf16
  u16* wb  = xb + 4194304;          // 4 x 1024x1024 bf16 (Wq,Wk,Wv,Wo)
  u16* qkv = wb + 4194304;          // Q,K,V each 4096x1024 bf16
  u16* ctx = qkv + 3 * 4194304;     // 4096x1024 bf16

  cvt_all<<<dim3(4096), dim3(256), 0, stream>>>(x, Wq, Wk, Wv, Wo, xb, wb);
  gemm_bt<0><<<dim3(32, 24), dim3(256), 0, stream>>>(xb, wb, qkv, nullptr, nullptr);
  attn<<<dim3(512), dim3(256), 0, stream>>>(qkv, qkv + 4194304, qkv + 8388608, ctx);
  gemm_bt<1><<<dim3(32, 8), dim3(256), 0, stream>>>(ctx, wb + 3 * 1048576, nullptr, out, bo);
}